// Round 1
// baseline (299.529 us; speedup 1.0000x reference)
//
#include <hip/hip_runtime.h>

// KernelRnn slow_update, fused.
// C=5 chemicals, R=14 rules, planes of P = M*N elements (2048*1024).
// h[p] = sum_c vy_c*chem[c][p]
//      + sum_c vz_c*tanh( sum_d K[c][d]*chem[d][p] )
//      + sum_r ( a_r*mean[r][p] + bi_r*var[r][p] - b_r*mean[r][p]^2 )
// with a_r = sum_c vz_c*Q[c][r], b_r = sum_c vz_c*Q[c][14+r], bi_r = b_r/time_index,
// vy_c = v_c*y_c, vz_c = v_c*z_c.
// Coefficients (83 floats) are computed once by prep_kernel into d_ws.

#define CC 5
#define RR 14

// d_ws float layout: [0..13]=a  [16..29]=bi  [32..45]=b  [48..52]=vy  [53..57]=vz  [58..82]=K
__global__ void prep_kernel(const float* __restrict__ Q,
                            const float* __restrict__ Ks,
                            const float* __restrict__ v,
                            const float* __restrict__ y,
                            const float* __restrict__ z,
                            const int* __restrict__ tindex,
                            float* __restrict__ cf) {
    int i = threadIdx.x;
    float inv_t = 1.0f / (float)tindex[0];
    if (i < RR) {
        float a = 0.0f, b = 0.0f;
        #pragma unroll
        for (int c = 0; c < CC; ++c) {
            float vz = v[c] * z[c];
            a = fmaf(vz, Q[c * (2 * RR) + i], a);
            b = fmaf(vz, Q[c * (2 * RR) + RR + i], b);
        }
        cf[i] = a;
        cf[16 + i] = b * inv_t;
        cf[32 + i] = b;
    } else if (i < RR + CC) {
        int c = i - RR;
        cf[48 + c] = v[c] * y[c];
        cf[53 + c] = v[c] * z[c];
    } else if (i < RR + CC + CC * CC) {
        int j = i - (RR + CC);
        cf[58 + j] = Ks[j];
    }
}

__device__ __forceinline__ float fast_tanh(float x) {
    // tanh(x) = 1 - 2/(exp(2x)+1); argument here is tiny (|x| ~ 0.02-0.2)
    float e = __expf(2.0f * x);
    return fmaf(-2.0f, __builtin_amdgcn_rcpf(e + 1.0f), 1.0f);
}

__global__ __launch_bounds__(256)
void fused_kernel(const float* __restrict__ chem,
                  const float* __restrict__ meanu,
                  const float* __restrict__ varu,
                  const float* __restrict__ cf,
                  float* __restrict__ out,
                  int P) {
    int t = blockIdx.x * blockDim.x + threadIdx.x;
    int p = t * 4;
    if (p >= P) return;  // P is a multiple of 4 for this problem (2048*1024)

    // load all 5 chemical planes (float4 each)
    float4 ch[CC];
    #pragma unroll
    for (int c = 0; c < CC; ++c)
        ch[c] = *reinterpret_cast<const float4*>(chem + (size_t)c * P + p);

    // acc = sum_c vy_c * chem_c
    float4 acc = make_float4(0.f, 0.f, 0.f, 0.f);
    #pragma unroll
    for (int c = 0; c < CC; ++c) {
        float vy = cf[48 + c];
        acc.x = fmaf(vy, ch[c].x, acc.x);
        acc.y = fmaf(vy, ch[c].y, acc.y);
        acc.z = fmaf(vy, ch[c].z, acc.z);
        acc.w = fmaf(vy, ch[c].w, acc.w);
    }

    // acc += sum_c vz_c * tanh(K[c,:] . chem)
    #pragma unroll
    for (int c = 0; c < CC; ++c) {
        float4 s = make_float4(0.f, 0.f, 0.f, 0.f);
        #pragma unroll
        for (int d = 0; d < CC; ++d) {
            float k = cf[58 + c * CC + d];
            s.x = fmaf(k, ch[d].x, s.x);
            s.y = fmaf(k, ch[d].y, s.y);
            s.z = fmaf(k, ch[d].z, s.z);
            s.w = fmaf(k, ch[d].w, s.w);
        }
        float vz = cf[53 + c];
        acc.x = fmaf(vz, fast_tanh(s.x), acc.x);
        acc.y = fmaf(vz, fast_tanh(s.y), acc.y);
        acc.z = fmaf(vz, fast_tanh(s.z), acc.z);
        acc.w = fmaf(vz, fast_tanh(s.w), acc.w);
    }

    // acc += sum_r a_r*mean + bi_r*variance - b_r*mean^2
    #pragma unroll
    for (int r = 0; r < RR; ++r) {
        float4 mu = *reinterpret_cast<const float4*>(meanu + (size_t)r * P + p);
        float4 va = *reinterpret_cast<const float4*>(varu + (size_t)r * P + p);
        float ar = cf[r], bir = cf[16 + r], br = cf[32 + r];
        acc.x = fmaf(ar, mu.x, acc.x);
        acc.y = fmaf(ar, mu.y, acc.y);
        acc.z = fmaf(ar, mu.z, acc.z);
        acc.w = fmaf(ar, mu.w, acc.w);
        acc.x = fmaf(bir, va.x, acc.x);
        acc.y = fmaf(bir, va.y, acc.y);
        acc.z = fmaf(bir, va.z, acc.z);
        acc.w = fmaf(bir, va.w, acc.w);
        acc.x = fmaf(-br, mu.x * mu.x, acc.x);
        acc.y = fmaf(-br, mu.y * mu.y, acc.y);
        acc.z = fmaf(-br, mu.z * mu.z, acc.z);
        acc.w = fmaf(-br, mu.w * mu.w, acc.w);
    }

    *reinterpret_cast<float4*>(out + p) = acc;
}

extern "C" void kernel_launch(void* const* d_in, const int* in_sizes, int n_in,
                              void* d_out, int out_size, void* d_ws, size_t ws_size,
                              hipStream_t stream) {
    const float* chem  = (const float*)d_in[0];  // [C, M, N]
    const float* meanu = (const float*)d_in[1];  // [R, M, N]
    const float* varu  = (const float*)d_in[2];  // [R, M, N]
    const float* Q     = (const float*)d_in[3];  // [C, 2R]
    const float* Ks    = (const float*)d_in[4];  // [C, C]
    const float* v     = (const float*)d_in[5];  // [1, C]
    const float* y     = (const float*)d_in[6];  // [C]
    const float* z     = (const float*)d_in[7];  // [C]
    const int*   ti    = (const int*)d_in[8];    // scalar time_index

    float* cf = (float*)d_ws;    // 83 floats of coefficient scratch
    float* out = (float*)d_out;  // [M, N] float32

    prep_kernel<<<1, 64, 0, stream>>>(Q, Ks, v, y, z, ti, cf);

    int P = out_size;                       // M*N
    int nthreads = (P + 3) / 4;             // one float4 per thread
    int blocks = (nthreads + 255) / 256;
    fused_kernel<<<blocks, 256, 0, stream>>>(chem, meanu, varu, cf, out, P);
}

// Round 2
// 296.590 us; speedup vs baseline: 1.0099x; 1.0099x over previous
//
#include <hip/hip_runtime.h>

// KernelRnn slow_update, fused. C=5 chemicals, R=14 rules, P = M*N = 2048*1024.
// h[p] = sum_c vy_c*chem[c][p]
//      + sum_c vz_c*tanh( sum_d K[c][d]*chem[d][p] )
//      + sum_r ( a_r*mean[r][p] + bi_r*var[r][p] - b_r*mean[r][p]^2 )
// Coefficients (83 floats) computed once by prep_kernel into d_ws.
//
// R2 change vs R1: hoist ALL 33 float4 loads into registers before compute.
// R1 had VGPR=32 -> ~2 loads in flight -> latency-bound (17% HBM, 4.8% VALU).
// Deliberately trade occupancy (launch_bounds(256,2)) for 33-deep MLP/thread.

#define CC 5
#define RR 14

// d_ws float layout: [0..13]=a  [16..29]=bi  [32..45]=b  [48..52]=vy  [53..57]=vz  [58..82]=K
__global__ void prep_kernel(const float* __restrict__ Q,
                            const float* __restrict__ Ks,
                            const float* __restrict__ v,
                            const float* __restrict__ y,
                            const float* __restrict__ z,
                            const int* __restrict__ tindex,
                            float* __restrict__ cf) {
    int i = threadIdx.x;
    float inv_t = 1.0f / (float)tindex[0];
    if (i < RR) {
        float a = 0.0f, b = 0.0f;
        #pragma unroll
        for (int c = 0; c < CC; ++c) {
            float vz = v[c] * z[c];
            a = fmaf(vz, Q[c * (2 * RR) + i], a);
            b = fmaf(vz, Q[c * (2 * RR) + RR + i], b);
        }
        cf[i] = a;
        cf[16 + i] = b * inv_t;
        cf[32 + i] = b;
    } else if (i < RR + CC) {
        int c = i - RR;
        cf[48 + c] = v[c] * y[c];
        cf[53 + c] = v[c] * z[c];
    } else if (i < RR + CC + CC * CC) {
        int j = i - (RR + CC);
        cf[58 + j] = Ks[j];
    }
}

__device__ __forceinline__ float fast_tanh(float x) {
    // tanh(x) = 1 - 2/(exp(2x)+1); argument here is tiny (|x| <~ 0.2)
    float e = __expf(2.0f * x);
    return fmaf(-2.0f, __builtin_amdgcn_rcpf(e + 1.0f), 1.0f);
}

__global__ __launch_bounds__(256, 2)
void fused_kernel(const float* __restrict__ chem,
                  const float* __restrict__ meanu,
                  const float* __restrict__ varu,
                  const float* __restrict__ cf,
                  float* __restrict__ out,
                  int P) {
    int t = blockIdx.x * blockDim.x + threadIdx.x;
    int p = t * 4;
    if (p >= P) return;  // P is a multiple of 4 (2048*1024)

    // ---- Issue ALL loads first: 33 outstanding float4 loads per thread ----
    float4 ch[CC];
    float4 mu[RR];
    float4 va[RR];
    #pragma unroll
    for (int c = 0; c < CC; ++c)
        ch[c] = *reinterpret_cast<const float4*>(chem + (size_t)c * P + p);
    #pragma unroll
    for (int r = 0; r < RR; ++r)
        mu[r] = *reinterpret_cast<const float4*>(meanu + (size_t)r * P + p);
    #pragma unroll
    for (int r = 0; r < RR; ++r)
        va[r] = *reinterpret_cast<const float4*>(varu + (size_t)r * P + p);

    // ---- Compute (consumes loads roughly in issue order) ----
    // acc = sum_c vy_c * chem_c
    float4 acc = make_float4(0.f, 0.f, 0.f, 0.f);
    #pragma unroll
    for (int c = 0; c < CC; ++c) {
        float vy = cf[48 + c];
        acc.x = fmaf(vy, ch[c].x, acc.x);
        acc.y = fmaf(vy, ch[c].y, acc.y);
        acc.z = fmaf(vy, ch[c].z, acc.z);
        acc.w = fmaf(vy, ch[c].w, acc.w);
    }

    // acc += sum_c vz_c * tanh(K[c,:] . chem)
    #pragma unroll
    for (int c = 0; c < CC; ++c) {
        float4 s = make_float4(0.f, 0.f, 0.f, 0.f);
        #pragma unroll
        for (int d = 0; d < CC; ++d) {
            float k = cf[58 + c * CC + d];
            s.x = fmaf(k, ch[d].x, s.x);
            s.y = fmaf(k, ch[d].y, s.y);
            s.z = fmaf(k, ch[d].z, s.z);
            s.w = fmaf(k, ch[d].w, s.w);
        }
        float vz = cf[53 + c];
        acc.x = fmaf(vz, fast_tanh(s.x), acc.x);
        acc.y = fmaf(vz, fast_tanh(s.y), acc.y);
        acc.z = fmaf(vz, fast_tanh(s.z), acc.z);
        acc.w = fmaf(vz, fast_tanh(s.w), acc.w);
    }

    // acc += sum_r a_r*mean + bi_r*variance - b_r*mean^2
    #pragma unroll
    for (int r = 0; r < RR; ++r) {
        float ar = cf[r], bir = cf[16 + r], br = cf[32 + r];
        acc.x = fmaf(ar, mu[r].x, acc.x);
        acc.y = fmaf(ar, mu[r].y, acc.y);
        acc.z = fmaf(ar, mu[r].z, acc.z);
        acc.w = fmaf(ar, mu[r].w, acc.w);
        acc.x = fmaf(bir, va[r].x, acc.x);
        acc.y = fmaf(bir, va[r].y, acc.y);
        acc.z = fmaf(bir, va[r].z, acc.z);
        acc.w = fmaf(bir, va[r].w, acc.w);
        acc.x = fmaf(-br, mu[r].x * mu[r].x, acc.x);
        acc.y = fmaf(-br, mu[r].y * mu[r].y, acc.y);
        acc.z = fmaf(-br, mu[r].z * mu[r].z, acc.z);
        acc.w = fmaf(-br, mu[r].w * mu[r].w, acc.w);
    }

    *reinterpret_cast<float4*>(out + p) = acc;
}

extern "C" void kernel_launch(void* const* d_in, const int* in_sizes, int n_in,
                              void* d_out, int out_size, void* d_ws, size_t ws_size,
                              hipStream_t stream) {
    const float* chem  = (const float*)d_in[0];  // [C, M, N]
    const float* meanu = (const float*)d_in[1];  // [R, M, N]
    const float* varu  = (const float*)d_in[2];  // [R, M, N]
    const float* Q     = (const float*)d_in[3];  // [C, 2R]
    const float* Ks    = (const float*)d_in[4];  // [C, C]
    const float* v     = (const float*)d_in[5];  // [1, C]
    const float* y     = (const float*)d_in[6];  // [C]
    const float* z     = (const float*)d_in[7];  // [C]
    const int*   ti    = (const int*)d_in[8];    // scalar time_index

    float* cf = (float*)d_ws;    // 83 floats of coefficient scratch
    float* out = (float*)d_out;  // [M, N] float32

    prep_kernel<<<1, 64, 0, stream>>>(Q, Ks, v, y, z, ti, cf);

    int P = out_size;                       // M*N
    int nthreads = (P + 3) / 4;             // one float4 per thread
    int blocks = (nthreads + 255) / 256;
    fused_kernel<<<blocks, 256, 0, stream>>>(chem, meanu, varu, cf, out, P);
}

// Round 3
// 292.072 us; speedup vs baseline: 1.0255x; 1.0155x over previous
//
#include <hip/hip_runtime.h>

// KernelRnn slow_update, fused. C=5 chemicals, R=14 rules, P = M*N = 2048*1024.
// h[p] = sum_c vy_c*chem[c][p]
//      + sum_c vz_c*tanh( sum_d K[c][d]*chem[d][p] )
//      + sum_r ( a_r*mean[r][p] + bi_r*var[r][p] - b_r*mean[r][p]^2 )
// Coefficients (83 floats) computed once by prep_kernel into d_ws.
//
// R3 change vs R2: sched_barrier(0) between the 33-load block and compute.
// R2's source-level hoist was undone by the scheduler (VGPR stayed 36 ->
// ~2 loads in flight -> 2.2 B/cyc/CU, latency-bound). sched_barrier pins
// all 33 global_load_dwordx4 before any consumer, forcing graduated vmcnt
// waits and ~33 KB in flight per wave. Occupancy loss (VGPR ~170) is the
// intended trade: 9 KB/CU in flight suffices to saturate HBM drain.

#define CC 5
#define RR 14

// d_ws float layout: [0..13]=a  [16..29]=bi  [32..45]=b  [48..52]=vy  [53..57]=vz  [58..82]=K
__global__ void prep_kernel(const float* __restrict__ Q,
                            const float* __restrict__ Ks,
                            const float* __restrict__ v,
                            const float* __restrict__ y,
                            const float* __restrict__ z,
                            const int* __restrict__ tindex,
                            float* __restrict__ cf) {
    int i = threadIdx.x;
    float inv_t = 1.0f / (float)tindex[0];
    if (i < RR) {
        float a = 0.0f, b = 0.0f;
        #pragma unroll
        for (int c = 0; c < CC; ++c) {
            float vz = v[c] * z[c];
            a = fmaf(vz, Q[c * (2 * RR) + i], a);
            b = fmaf(vz, Q[c * (2 * RR) + RR + i], b);
        }
        cf[i] = a;
        cf[16 + i] = b * inv_t;
        cf[32 + i] = b;
    } else if (i < RR + CC) {
        int c = i - RR;
        cf[48 + c] = v[c] * y[c];
        cf[53 + c] = v[c] * z[c];
    } else if (i < RR + CC + CC * CC) {
        int j = i - (RR + CC);
        cf[58 + j] = Ks[j];
    }
}

__device__ __forceinline__ float fast_tanh(float x) {
    // tanh(x) = 1 - 2/(exp(2x)+1); argument here is tiny (|x| <~ 0.2)
    float e = __expf(2.0f * x);
    return fmaf(-2.0f, __builtin_amdgcn_rcpf(e + 1.0f), 1.0f);
}

__global__ __launch_bounds__(256)
void fused_kernel(const float* __restrict__ chem,
                  const float* __restrict__ meanu,
                  const float* __restrict__ varu,
                  const float* __restrict__ cf,
                  float* __restrict__ out,
                  int P) {
    int t = blockIdx.x * blockDim.x + threadIdx.x;
    int p = t * 4;
    if (p >= P) return;  // P is a multiple of 4 (2048*1024)

    // ---- Issue ALL 33 loads; sched_barrier forbids sinking them to uses ----
    float4 mu[RR];
    float4 va[RR];
    float4 ch[CC];
    #pragma unroll
    for (int r = 0; r < RR; ++r) {
        mu[r] = *reinterpret_cast<const float4*>(meanu + (size_t)r * P + p);
        va[r] = *reinterpret_cast<const float4*>(varu + (size_t)r * P + p);
    }
    #pragma unroll
    for (int c = 0; c < CC; ++c)
        ch[c] = *reinterpret_cast<const float4*>(chem + (size_t)c * P + p);

    __builtin_amdgcn_sched_barrier(0);  // nothing moves across this point

    // ---- Consume in load order -> graduated vmcnt(N) waits ----
    // rules first: r-th iteration only needs loads #2r,#2r+1; the rest
    // (and all 5 chem loads) remain outstanding.
    float4 acc = make_float4(0.f, 0.f, 0.f, 0.f);
    #pragma unroll
    for (int r = 0; r < RR; ++r) {
        float ar = cf[r], bir = cf[16 + r], br = cf[32 + r];
        acc.x = fmaf(ar, mu[r].x, acc.x);
        acc.y = fmaf(ar, mu[r].y, acc.y);
        acc.z = fmaf(ar, mu[r].z, acc.z);
        acc.w = fmaf(ar, mu[r].w, acc.w);
        acc.x = fmaf(bir, va[r].x, acc.x);
        acc.y = fmaf(bir, va[r].y, acc.y);
        acc.z = fmaf(bir, va[r].z, acc.z);
        acc.w = fmaf(bir, va[r].w, acc.w);
        acc.x = fmaf(-br, mu[r].x * mu[r].x, acc.x);
        acc.y = fmaf(-br, mu[r].y * mu[r].y, acc.y);
        acc.z = fmaf(-br, mu[r].z * mu[r].z, acc.z);
        acc.w = fmaf(-br, mu[r].w * mu[r].w, acc.w);
    }

    // chem decay term
    #pragma unroll
    for (int c = 0; c < CC; ++c) {
        float vy = cf[48 + c];
        acc.x = fmaf(vy, ch[c].x, acc.x);
        acc.y = fmaf(vy, ch[c].y, acc.y);
        acc.z = fmaf(vy, ch[c].z, acc.z);
        acc.w = fmaf(vy, ch[c].w, acc.w);
    }

    // tanh mixing term
    #pragma unroll
    for (int c = 0; c < CC; ++c) {
        float4 s = make_float4(0.f, 0.f, 0.f, 0.f);
        #pragma unroll
        for (int d = 0; d < CC; ++d) {
            float k = cf[58 + c * CC + d];
            s.x = fmaf(k, ch[d].x, s.x);
            s.y = fmaf(k, ch[d].y, s.y);
            s.z = fmaf(k, ch[d].z, s.z);
            s.w = fmaf(k, ch[d].w, s.w);
        }
        float vz = cf[53 + c];
        acc.x = fmaf(vz, fast_tanh(s.x), acc.x);
        acc.y = fmaf(vz, fast_tanh(s.y), acc.y);
        acc.z = fmaf(vz, fast_tanh(s.z), acc.z);
        acc.w = fmaf(vz, fast_tanh(s.w), acc.w);
    }

    *reinterpret_cast<float4*>(out + p) = acc;
}

extern "C" void kernel_launch(void* const* d_in, const int* in_sizes, int n_in,
                              void* d_out, int out_size, void* d_ws, size_t ws_size,
                              hipStream_t stream) {
    const float* chem  = (const float*)d_in[0];  // [C, M, N]
    const float* meanu = (const float*)d_in[1];  // [R, M, N]
    const float* varu  = (const float*)d_in[2];  // [R, M, N]
    const float* Q     = (const float*)d_in[3];  // [C, 2R]
    const float* Ks    = (const float*)d_in[4];  // [C, C]
    const float* v     = (const float*)d_in[5];  // [1, C]
    const float* y     = (const float*)d_in[6];  // [C]
    const float* z     = (const float*)d_in[7];  // [C]
    const int*   ti    = (const int*)d_in[8];    // scalar time_index

    float* cf = (float*)d_ws;    // 83 floats of coefficient scratch
    float* out = (float*)d_out;  // [M, N] float32

    prep_kernel<<<1, 64, 0, stream>>>(Q, Ks, v, y, z, ti, cf);

    int P = out_size;                       // M*N
    int nthreads = (P + 3) / 4;             // one float4 per thread
    int blocks = (nthreads + 255) / 256;
    fused_kernel<<<blocks, 256, 0, stream>>>(chem, meanu, varu, cf, out, P);
}

// Round 4
// 288.372 us; speedup vs baseline: 1.0387x; 1.0128x over previous
//
#include <hip/hip_runtime.h>

// KernelRnn slow_update, fused. C=5 chemicals, R=14 rules, P = M*N = 2048*1024.
// h[p] = sum_c vy_c*chem[c][p]
//      + sum_c vz_c*tanh( sum_d K[c][d]*chem[d][p] )
//      + sum_r ( a_r*mean[r][p] + bi_r*var[r][p] - b_r*mean[r][p]^2 )
// Coefficients (83 floats) computed once by prep_kernel into d_ws.
//
// R4 change vs R3: plane-by-plane streaming. R1-R3 all plateaued at the
// SAME 1.33 TB/s regardless of occupancy (19-54%) and per-wave MLP (VGPR
// 32-88) -> limiter is not request count. Planes are exactly 8 MiB apart,
// so a thread's 33 same-offset loads alias into one L1/L2 set; same-set
// fill serialization collapses per-CU memory parallelism. Fix: each block
// owns a contiguous 2048-float tile and streams ONE (mean,var) plane pair
// per r-iteration (rolled loop, unroll 1 -> streams separated in TIME),
// carrying float4 accumulators. Chem phase touches 5 planes (< assoc).

#define CC 5
#define RR 14
#define VU 2   // float4 units per thread; tile = 256*VU*4 = 2048 floats

// d_ws float layout: [0..13]=a  [16..29]=bi  [32..45]=b  [48..52]=vy  [53..57]=vz  [58..82]=K
__global__ void prep_kernel(const float* __restrict__ Q,
                            const float* __restrict__ Ks,
                            const float* __restrict__ v,
                            const float* __restrict__ y,
                            const float* __restrict__ z,
                            const int* __restrict__ tindex,
                            float* __restrict__ cf) {
    int i = threadIdx.x;
    float inv_t = 1.0f / (float)tindex[0];
    if (i < RR) {
        float a = 0.0f, b = 0.0f;
        #pragma unroll
        for (int c = 0; c < CC; ++c) {
            float vz = v[c] * z[c];
            a = fmaf(vz, Q[c * (2 * RR) + i], a);
            b = fmaf(vz, Q[c * (2 * RR) + RR + i], b);
        }
        cf[i] = a;
        cf[16 + i] = b * inv_t;
        cf[32 + i] = b;
    } else if (i < RR + CC) {
        int c = i - RR;
        cf[48 + c] = v[c] * y[c];
        cf[53 + c] = v[c] * z[c];
    } else if (i < RR + CC + CC * CC) {
        int j = i - (RR + CC);
        cf[58 + j] = Ks[j];
    }
}

__device__ __forceinline__ float fast_tanh(float x) {
    // tanh(x) = 1 - 2/(exp(2x)+1); argument here is tiny (|x| <~ 0.2)
    float e = __expf(2.0f * x);
    return fmaf(-2.0f, __builtin_amdgcn_rcpf(e + 1.0f), 1.0f);
}

__global__ __launch_bounds__(256)
void fused_kernel(const float* __restrict__ chem,
                  const float* __restrict__ meanu,
                  const float* __restrict__ varu,
                  const float* __restrict__ cf,
                  float* __restrict__ out,
                  int P) {
    const int tid = threadIdx.x;
    const size_t tile = (size_t)blockIdx.x * (256 * VU * 4);  // in floats

    float4 acc[VU];
    #pragma unroll
    for (int u = 0; u < VU; ++u) acc[u] = make_float4(0.f, 0.f, 0.f, 0.f);

    // ---- Phase A: rules, one (mean_r, var_r) plane pair per iteration ----
    #pragma unroll 1   // keep planes time-separated; do NOT recreate 28 streams
    for (int r = 0; r < RR; ++r) {
        const float4* pm = reinterpret_cast<const float4*>(meanu + (size_t)r * P + tile);
        const float4* pv = reinterpret_cast<const float4*>(varu  + (size_t)r * P + tile);
        float4 m[VU], w[VU];
        #pragma unroll
        for (int u = 0; u < VU; ++u) m[u] = pm[u * 256 + tid];
        #pragma unroll
        for (int u = 0; u < VU; ++u) w[u] = pv[u * 256 + tid];
        float ar = cf[r], bir = cf[16 + r], br = cf[32 + r];
        #pragma unroll
        for (int u = 0; u < VU; ++u) {
            acc[u].x = fmaf(ar, m[u].x, acc[u].x);
            acc[u].y = fmaf(ar, m[u].y, acc[u].y);
            acc[u].z = fmaf(ar, m[u].z, acc[u].z);
            acc[u].w = fmaf(ar, m[u].w, acc[u].w);
            acc[u].x = fmaf(bir, w[u].x, acc[u].x);
            acc[u].y = fmaf(bir, w[u].y, acc[u].y);
            acc[u].z = fmaf(bir, w[u].z, acc[u].z);
            acc[u].w = fmaf(bir, w[u].w, acc[u].w);
            acc[u].x = fmaf(-br, m[u].x * m[u].x, acc[u].x);
            acc[u].y = fmaf(-br, m[u].y * m[u].y, acc[u].y);
            acc[u].z = fmaf(-br, m[u].z * m[u].z, acc[u].z);
            acc[u].w = fmaf(-br, m[u].w * m[u].w, acc[u].w);
        }
    }

    // ---- Phase B: chemicals (5 planes live — needed for tanh coupling) ----
    float4 ch[CC][VU];
    #pragma unroll
    for (int c = 0; c < CC; ++c) {
        const float4* pc = reinterpret_cast<const float4*>(chem + (size_t)c * P + tile);
        #pragma unroll
        for (int u = 0; u < VU; ++u) ch[c][u] = pc[u * 256 + tid];
    }

    #pragma unroll
    for (int u = 0; u < VU; ++u) {
        // decay term: sum_c vy_c * chem_c
        #pragma unroll
        for (int c = 0; c < CC; ++c) {
            float vy = cf[48 + c];
            acc[u].x = fmaf(vy, ch[c][u].x, acc[u].x);
            acc[u].y = fmaf(vy, ch[c][u].y, acc[u].y);
            acc[u].z = fmaf(vy, ch[c][u].z, acc[u].z);
            acc[u].w = fmaf(vy, ch[c][u].w, acc[u].w);
        }
        // mixing term: sum_c vz_c * tanh(K[c,:] . chem)
        #pragma unroll
        for (int c = 0; c < CC; ++c) {
            float4 s = make_float4(0.f, 0.f, 0.f, 0.f);
            #pragma unroll
            for (int d = 0; d < CC; ++d) {
                float k = cf[58 + c * CC + d];
                s.x = fmaf(k, ch[d][u].x, s.x);
                s.y = fmaf(k, ch[d][u].y, s.y);
                s.z = fmaf(k, ch[d][u].z, s.z);
                s.w = fmaf(k, ch[d][u].w, s.w);
            }
            float vz = cf[53 + c];
            acc[u].x = fmaf(vz, fast_tanh(s.x), acc[u].x);
            acc[u].y = fmaf(vz, fast_tanh(s.y), acc[u].y);
            acc[u].z = fmaf(vz, fast_tanh(s.z), acc[u].z);
            acc[u].w = fmaf(vz, fast_tanh(s.w), acc[u].w);
        }
    }

    float4* po = reinterpret_cast<float4*>(out + tile);
    #pragma unroll
    for (int u = 0; u < VU; ++u) po[u * 256 + tid] = acc[u];
}

extern "C" void kernel_launch(void* const* d_in, const int* in_sizes, int n_in,
                              void* d_out, int out_size, void* d_ws, size_t ws_size,
                              hipStream_t stream) {
    const float* chem  = (const float*)d_in[0];  // [C, M, N]
    const float* meanu = (const float*)d_in[1];  // [R, M, N]
    const float* varu  = (const float*)d_in[2];  // [R, M, N]
    const float* Q     = (const float*)d_in[3];  // [C, 2R]
    const float* Ks    = (const float*)d_in[4];  // [C, C]
    const float* v     = (const float*)d_in[5];  // [1, C]
    const float* y     = (const float*)d_in[6];  // [C]
    const float* z     = (const float*)d_in[7];  // [C]
    const int*   ti    = (const int*)d_in[8];    // scalar time_index

    float* cf = (float*)d_ws;    // 83 floats of coefficient scratch
    float* out = (float*)d_out;  // [M, N] float32

    prep_kernel<<<1, 64, 0, stream>>>(Q, Ks, v, y, z, ti, cf);

    int P = out_size;                         // M*N = 2097152
    int tile_elems = 256 * VU * 4;            // 2048 floats per block
    int blocks = (P + tile_elems - 1) / tile_elems;
    fused_kernel<<<blocks, 256, 0, stream>>>(chem, meanu, varu, cf, out, P);
}

// Round 5
// 264.333 us; speedup vs baseline: 1.1331x; 1.0909x over previous
//
#include <hip/hip_runtime.h>

// KernelRnn slow_update, fused. C=5 chemicals, R=14 rules, P = M*N = 2048*1024.
// h[p] = sum_c vy_c*chem[c][p]
//      + sum_c vz_c*tanh( sum_d K[c][d]*chem[d][p] )
//      + sum_r ( a_r*mean[r][p] + bi_r*var[r][p] - b_r*mean[r][p]^2 )
// Coefficients (83 floats) computed once by prep_kernel into d_ws.
//
// R5 change vs R4 (single variable): plane loads are NON-TEMPORAL.
// R1-R4 are invariant at ~105us / 2.7 TB/s L1-traffic (~4.4 B/cyc/CU)
// across occupancy 19-54% and per-wave MLP 2-33 -> per-CU cap, consistent
// with TCP MSHR/set-thrash: 33 planes sit exactly 8 MiB apart, so every
// thread's loads alias the same L1 sets; every access is an L1 miss and
// allocates. nt (evict-first / no-allocate hint) takes L1 thrash out of
// the path. If this is also invariant, the cap is below L1 -> pivot.

#define CC 5
#define RR 14
#define VU 2   // float4 units per thread; tile = 256*VU*4 = 2048 floats

typedef float f32x4 __attribute__((ext_vector_type(4)));

// d_ws float layout: [0..13]=a  [16..29]=bi  [32..45]=b  [48..52]=vy  [53..57]=vz  [58..82]=K
__global__ void prep_kernel(const float* __restrict__ Q,
                            const float* __restrict__ Ks,
                            const float* __restrict__ v,
                            const float* __restrict__ y,
                            const float* __restrict__ z,
                            const int* __restrict__ tindex,
                            float* __restrict__ cf) {
    int i = threadIdx.x;
    float inv_t = 1.0f / (float)tindex[0];
    if (i < RR) {
        float a = 0.0f, b = 0.0f;
        #pragma unroll
        for (int c = 0; c < CC; ++c) {
            float vz = v[c] * z[c];
            a = fmaf(vz, Q[c * (2 * RR) + i], a);
            b = fmaf(vz, Q[c * (2 * RR) + RR + i], b);
        }
        cf[i] = a;
        cf[16 + i] = b * inv_t;
        cf[32 + i] = b;
    } else if (i < RR + CC) {
        int c = i - RR;
        cf[48 + c] = v[c] * y[c];
        cf[53 + c] = v[c] * z[c];
    } else if (i < RR + CC + CC * CC) {
        int j = i - (RR + CC);
        cf[58 + j] = Ks[j];
    }
}

__device__ __forceinline__ float fast_tanh(float x) {
    // tanh(x) = 1 - 2/(exp(2x)+1); argument here is tiny (|x| <~ 0.2)
    float e = __expf(2.0f * x);
    return fmaf(-2.0f, __builtin_amdgcn_rcpf(e + 1.0f), 1.0f);
}

__global__ __launch_bounds__(256)
void fused_kernel(const float* __restrict__ chem,
                  const float* __restrict__ meanu,
                  const float* __restrict__ varu,
                  const float* __restrict__ cf,
                  float* __restrict__ out,
                  int P) {
    const int tid = threadIdx.x;
    const size_t tile = (size_t)blockIdx.x * (256 * VU * 4);  // in floats

    f32x4 acc[VU];
    #pragma unroll
    for (int u = 0; u < VU; ++u) acc[u] = (f32x4)(0.f);

    // ---- Phase A: rules, one (mean_r, var_r) plane pair per iteration ----
    #pragma unroll 1
    for (int r = 0; r < RR; ++r) {
        const f32x4* pm = reinterpret_cast<const f32x4*>(meanu + (size_t)r * P + tile);
        const f32x4* pv = reinterpret_cast<const f32x4*>(varu  + (size_t)r * P + tile);
        f32x4 m[VU], w[VU];
        #pragma unroll
        for (int u = 0; u < VU; ++u) m[u] = __builtin_nontemporal_load(pm + u * 256 + tid);
        #pragma unroll
        for (int u = 0; u < VU; ++u) w[u] = __builtin_nontemporal_load(pv + u * 256 + tid);
        float ar = cf[r], bir = cf[16 + r], br = cf[32 + r];
        #pragma unroll
        for (int u = 0; u < VU; ++u) {
            acc[u].x = fmaf(ar, m[u].x, acc[u].x);
            acc[u].y = fmaf(ar, m[u].y, acc[u].y);
            acc[u].z = fmaf(ar, m[u].z, acc[u].z);
            acc[u].w = fmaf(ar, m[u].w, acc[u].w);
            acc[u].x = fmaf(bir, w[u].x, acc[u].x);
            acc[u].y = fmaf(bir, w[u].y, acc[u].y);
            acc[u].z = fmaf(bir, w[u].z, acc[u].z);
            acc[u].w = fmaf(bir, w[u].w, acc[u].w);
            acc[u].x = fmaf(-br, m[u].x * m[u].x, acc[u].x);
            acc[u].y = fmaf(-br, m[u].y * m[u].y, acc[u].y);
            acc[u].z = fmaf(-br, m[u].z * m[u].z, acc[u].z);
            acc[u].w = fmaf(-br, m[u].w * m[u].w, acc[u].w);
        }
    }

    // ---- Phase B: chemicals (5 planes live — needed for tanh coupling) ----
    f32x4 ch[CC][VU];
    #pragma unroll
    for (int c = 0; c < CC; ++c) {
        const f32x4* pc = reinterpret_cast<const f32x4*>(chem + (size_t)c * P + tile);
        #pragma unroll
        for (int u = 0; u < VU; ++u) ch[c][u] = __builtin_nontemporal_load(pc + u * 256 + tid);
    }

    #pragma unroll
    for (int u = 0; u < VU; ++u) {
        // decay term: sum_c vy_c * chem_c
        #pragma unroll
        for (int c = 0; c < CC; ++c) {
            float vy = cf[48 + c];
            acc[u].x = fmaf(vy, ch[c][u].x, acc[u].x);
            acc[u].y = fmaf(vy, ch[c][u].y, acc[u].y);
            acc[u].z = fmaf(vy, ch[c][u].z, acc[u].z);
            acc[u].w = fmaf(vy, ch[c][u].w, acc[u].w);
        }
        // mixing term: sum_c vz_c * tanh(K[c,:] . chem)
        #pragma unroll
        for (int c = 0; c < CC; ++c) {
            f32x4 s = (f32x4)(0.f);
            #pragma unroll
            for (int d = 0; d < CC; ++d) {
                float k = cf[58 + c * CC + d];
                s.x = fmaf(k, ch[d][u].x, s.x);
                s.y = fmaf(k, ch[d][u].y, s.y);
                s.z = fmaf(k, ch[d][u].z, s.z);
                s.w = fmaf(k, ch[d][u].w, s.w);
            }
            float vz = cf[53 + c];
            acc[u].x = fmaf(vz, fast_tanh(s.x), acc[u].x);
            acc[u].y = fmaf(vz, fast_tanh(s.y), acc[u].y);
            acc[u].z = fmaf(vz, fast_tanh(s.z), acc[u].z);
            acc[u].w = fmaf(vz, fast_tanh(s.w), acc[u].w);
        }
    }

    f32x4* po = reinterpret_cast<f32x4*>(out + tile);
    #pragma unroll
    for (int u = 0; u < VU; ++u) po[u * 256 + tid] = acc[u];
}

extern "C" void kernel_launch(void* const* d_in, const int* in_sizes, int n_in,
                              void* d_out, int out_size, void* d_ws, size_t ws_size,
                              hipStream_t stream) {
    const float* chem  = (const float*)d_in[0];  // [C, M, N]
    const float* meanu = (const float*)d_in[1];  // [R, M, N]
    const float* varu  = (const float*)d_in[2];  // [R, M, N]
    const float* Q     = (const float*)d_in[3];  // [C, 2R]
    const float* Ks    = (const float*)d_in[4];  // [C, C]
    const float* v     = (const float*)d_in[5];  // [1, C]
    const float* y     = (const float*)d_in[6];  // [C]
    const float* z     = (const float*)d_in[7];  // [C]
    const int*   ti    = (const int*)d_in[8];    // scalar time_index

    float* cf = (float*)d_ws;    // 83 floats of coefficient scratch
    float* out = (float*)d_out;  // [M, N] float32

    prep_kernel<<<1, 64, 0, stream>>>(Q, Ks, v, y, z, ti, cf);

    int P = out_size;                         // M*N = 2097152
    int tile_elems = 256 * VU * 4;            // 2048 floats per block
    int blocks = (P + tile_elems - 1) / tile_elems;
    fused_kernel<<<blocks, 256, 0, stream>>>(chem, meanu, varu, cf, out, P);
}